// Round 12
// baseline (302.949 us; speedup 1.0000x reference)
//
#include <hip/hip_runtime.h>

#define B_ 256
#define L_ 50
#define D_ 128
#define T_ 4
#define NH 8
#define NV 4
#define TB_ (T_*B_)
#define EPSF 1e-5f

typedef _Float16 h8 __attribute__((ext_vector_type(8)));
typedef float f4 __attribute__((ext_vector_type(4)));

__device__ __forceinline__ float waveSum(float v) {
    #pragma unroll
    for (int o = 32; o > 0; o >>= 1) v += __shfl_down(v, o, 64);
    return v;
}

// element offset of scale i inside y buffer: 1024*8*sum_{i'<i}(50-i')
__device__ __forceinline__ size_t yoff(int i) {
    return (size_t)8192 * (size_t)(50 * i - (i * (i - 1)) / 2);
}

// K0: split conv_h_w fp32 -> fp16 (hi | lo*1024), [i][dk][c=16][d] with
// 16B-granule pre-swizzle (granule gd stored at gd^c); zero-pad dk>i, i>=50.
__global__ __launch_bounds__(256) void k0_wsplit(
        const float* __restrict__ w, _Float16* __restrict__ whl) {
    int dk = blockIdx.x, i = blockIdx.y;
    int t = threadIdx.x;
    int c = t >> 4, gd = t & 15;
    int h = c & 7;
    bool live = (i < 50) && (dk <= i);
    const float* src = w + (((size_t)i * NH + h) * L_ + dk) * D_ + gd * 8;
    h8 o;
    #pragma unroll
    for (int e = 0; e < 8; ++e) {
        float wv = live ? src[e] : 0.f;
        _Float16 hi = (_Float16)wv;
        o[e] = (c < 8) ? hi : (_Float16)((wv - (float)hi) * 1024.f);
    }
    *(h8*)(whl + (((size_t)i * 50 + dk) * 16 + c) * 128 + ((gd ^ c) & 15) * 8) = o;
}

// K1: embedding + LayerNorm + LIF(T=4) -> s16 [T*B][L][D] fp16 PRE-SWIZZLED, smean fp32
__global__ __launch_bounds__(128) void k1_embed_ln_lif(
        const int* __restrict__ item, const float* __restrict__ tab,
        const float* __restrict__ g, const float* __restrict__ be,
        _Float16* __restrict__ s16, float* __restrict__ smean) {
    int bid = blockIdx.x;
    int b = bid / L_, l = bid % L_;
    int d = threadIdx.x;
    int wid = d >> 6, lane = d & 63;
    __shared__ float red[2];
    int it = item[b * L_ + l];
    float e = tab[(size_t)it * D_ + d];
    float sm_ = waveSum(e);
    if (lane == 0) red[wid] = sm_;
    __syncthreads();
    float mu = (red[0] + red[1]) * (1.f / 128.f);
    __syncthreads();
    float df = e - mu;
    float s2 = waveSum(df * df);
    if (lane == 0) red[wid] = s2;
    __syncthreads();
    float var = (red[0] + red[1]) * (1.f / 128.f);
    float x = df / sqrtf(var + EPSF) * g[d] + be[d];
    float v = 0.f, acc = 0.f;
    int pos = (((d >> 3) ^ l) & 15) * 8 + (d & 7);   // pre-swizzled slot
    #pragma unroll
    for (int t = 0; t < T_; ++t) {
        v += (x - v) * 0.5f;
        float sp = (v >= 1.f) ? 1.f : 0.f;
        v *= (1.f - sp);
        s16[((size_t)(t * B_ + b) * L_ + l) * D_ + pos] = (_Float16)sp;
        acc += sp;
    }
    smean[((size_t)b * L_ + l) * D_ + d] = acc * 0.25f;
}

// ---- K2z: software-pipelined conv. 512 threads = 8 waves, 8 tb/block,
// 1 block/CU (102.4 KB A in LDS). Wave = (tq: 4-tb quad, dc slice).
// Per job (scale-group i0, 16-col j-window jw): acc[4 sc][4 tt].
// K-loop is barrier-free; A (LDS) and B (global, L1/L2-hot) fragments are
// 1-deep register-double-buffered: each phase ISSUES next-dk loads, then runs
// 16 MFMAs on current regs -> LDS/global latency hides under the MFMA cluster.
// dc-partials merged via the dead A-region at the end.

// 28 jobs, sorted by kmax descending for tail balance.
__device__ const int JZ_i0[28] = {
    48, 44, 40, 36, 32, 32, 28, 28, 24, 24, 20, 20,
    16, 16, 16, 12, 12, 12,  8,  8,  8,  4,  4,  4,  0,  0,  0,  0};
__device__ const int JZ_jw[28] = {
     0,  0,  0,  0,  0,  1,  0,  1,  0,  1,  0,  1,
     0,  1,  2,  0,  1,  2,  0,  1,  2,  0,  1,  2,  0,  1,  2,  3};

__global__ __launch_bounds__(512, 2) void k2z(
        const _Float16* __restrict__ s16, const _Float16* __restrict__ whl,
        float* __restrict__ y) {
    extern __shared__ __align__(16) char lds[];
    const int tbo = blockIdx.x;              // 8 tb per block
    const int i0 = JZ_i0[blockIdx.y];
    const int jw = JZ_jw[blockIdx.y];
    const int kmax = (i0 + 4 <= 50) ? (i0 + 4) : 50;   // always even
    const int tid = threadIdx.x;
    const int wave = tid >> 6, lane = tid & 63;
    const int tq = wave >> 2;                // tb-quad 0/1
    const int dc = wave & 3;                 // dc slice 0..3
    const int c_ = lane & 15, g = lane >> 4;
    const int dcg = (dc << 2) + g;

    // stage A once (linear copy; swizzle baked into s16)
    {
        const float4* src = (const float4*)(s16 + (size_t)tbo * 8 * (L_ * D_));
        float4* dst = (float4*)lds;
        for (int idx = tid; idx < 6400; idx += 512) dst[idx] = src[idx];
    }

    // per-lane B base: scale (i0+sc), chunk dk, fragment (c_, dc, g)
    const int boffc = c_ * 256 + ((dcg ^ c_) & 15) * 16;
    const char* gB = (const char*)whl + (size_t)i0 * 204800 + boffc;  // 204800=50*4096
    const char* ldsA = lds + tq * 4 * 12800;

    h8 aC[4], aN[4], bC[4], bN[4];
    // prologue: B for dk=0 (global, before barrier), A for dk=0 (after barrier)
    bC[0] = *(const h8*)(gB);
    bC[1] = *(const h8*)(gB + 204800);
    bC[2] = *(const h8*)(gB + 409600);
    bC[3] = *(const h8*)(gB + 614400);
    __syncthreads();                         // A staged
    {
        int l = jw * 16 + c_; if (l > 49) l = 49;
        const int ao = l * 256 + ((dcg ^ l) & 15) * 16;
        aC[0] = *(const h8*)(ldsA + ao);
        aC[1] = *(const h8*)(ldsA + 12800 + ao);
        aC[2] = *(const h8*)(ldsA + 25600 + ao);
        aC[3] = *(const h8*)(ldsA + 38400 + ao);
    }

    f4 acc[4][4];                            // [sc][tt]
    #pragma unroll
    for (int sc = 0; sc < 4; ++sc)
        #pragma unroll
        for (int tt = 0; tt < 4; ++tt) { f4 z = {0.f, 0.f, 0.f, 0.f}; acc[sc][tt] = z; }

    for (int dk = 0; dk < kmax; dk += 2) {
        // phase 0: issue loads for dk+1, MFMA on dk
        {
            const char* p = gB + (size_t)(dk + 1) * 4096;
            bN[0] = *(const h8*)(p);
            bN[1] = *(const h8*)(p + 204800);
            bN[2] = *(const h8*)(p + 409600);
            bN[3] = *(const h8*)(p + 614400);
            int l = jw * 16 + c_ + dk + 1; if (l > 49) l = 49;
            const int ao = l * 256 + ((dcg ^ l) & 15) * 16;
            aN[0] = *(const h8*)(ldsA + ao);
            aN[1] = *(const h8*)(ldsA + 12800 + ao);
            aN[2] = *(const h8*)(ldsA + 25600 + ao);
            aN[3] = *(const h8*)(ldsA + 38400 + ao);
        }
        __builtin_amdgcn_sched_barrier(0);   // loads above, MFMAs below
        #pragma unroll
        for (int tt = 0; tt < 4; ++tt) {
            acc[0][tt] = __builtin_amdgcn_mfma_f32_16x16x32_f16(aC[tt], bC[0], acc[0][tt], 0, 0, 0);
            acc[1][tt] = __builtin_amdgcn_mfma_f32_16x16x32_f16(aC[tt], bC[1], acc[1][tt], 0, 0, 0);
            acc[2][tt] = __builtin_amdgcn_mfma_f32_16x16x32_f16(aC[tt], bC[2], acc[2][tt], 0, 0, 0);
            acc[3][tt] = __builtin_amdgcn_mfma_f32_16x16x32_f16(aC[tt], bC[3], acc[3][tt], 0, 0, 0);
        }
        // phase 1: issue loads for dk+2 (if any), MFMA on dk+1
        if (dk + 2 < kmax) {
            const char* p = gB + (size_t)(dk + 2) * 4096;
            bC[0] = *(const h8*)(p);
            bC[1] = *(const h8*)(p + 204800);
            bC[2] = *(const h8*)(p + 409600);
            bC[3] = *(const h8*)(p + 614400);
            int l = jw * 16 + c_ + dk + 2; if (l > 49) l = 49;
            const int ao = l * 256 + ((dcg ^ l) & 15) * 16;
            aC[0] = *(const h8*)(ldsA + ao);
            aC[1] = *(const h8*)(ldsA + 12800 + ao);
            aC[2] = *(const h8*)(ldsA + 25600 + ao);
            aC[3] = *(const h8*)(ldsA + 38400 + ao);
        }
        __builtin_amdgcn_sched_barrier(0);
        #pragma unroll
        for (int tt = 0; tt < 4; ++tt) {
            acc[0][tt] = __builtin_amdgcn_mfma_f32_16x16x32_f16(aN[tt], bN[0], acc[0][tt], 0, 0, 0);
            acc[1][tt] = __builtin_amdgcn_mfma_f32_16x16x32_f16(aN[tt], bN[1], acc[1][tt], 0, 0, 0);
            acc[2][tt] = __builtin_amdgcn_mfma_f32_16x16x32_f16(aN[tt], bN[2], acc[2][tt], 0, 0, 0);
            acc[3][tt] = __builtin_amdgcn_mfma_f32_16x16x32_f16(aN[tt], bN[3], acc[3][tt], 0, 0, 0);
        }
    }

    // merge K-partials across dc=1..3 into dc=0 (A region dead after loop).
    // row = ((dc-1)*2+tq)*16 + sc*4+tt in [0,96); 96 x 64 x 16B = 96KB.
    __syncthreads();                         // all waves out of the dk-loop (A reads done)
    f4* mbuf = (f4*)lds;
    if (dc != 0) {
        f4* wp = mbuf + (size_t)(((dc - 1) * 2 + tq) * 16) * 64 + lane;
        #pragma unroll
        for (int sc = 0; sc < 4; ++sc)
            #pragma unroll
            for (int tt = 0; tt < 4; ++tt)
                wp[(sc * 4 + tt) * 64] = acc[sc][tt];
    }
    __syncthreads();
    if (dc == 0) {
        #pragma unroll
        for (int dd = 0; dd < 3; ++dd) {
            const f4* rp = mbuf + (size_t)((dd * 2 + tq) * 16) * 64 + lane;
            #pragma unroll
            for (int sc = 0; sc < 4; ++sc)
                #pragma unroll
                for (int tt = 0; tt < 4; ++tt)
                    acc[sc][tt] += rp[(sc * 4 + tt) * 64];
        }
        const bool hiLane = (c_ < 8);
        const int h = c_ & 7;
        #pragma unroll
        for (int sc = 0; sc < 4; ++sc) {
            const int i = i0 + sc;
            const int J = 50 - i;
            if (J <= 0) continue;
            #pragma unroll
            for (int tt = 0; tt < 4; ++tt) {
                const int tb = tbo * 8 + tq * 4 + tt;
                size_t yb = yoff(i) + ((size_t)tb * NH + h) * J;
                #pragma unroll
                for (int r = 0; r < 4; ++r) {
                    float lo = __shfl_xor(acc[sc][tt][r], 8, 64);
                    int j = jw * 16 + g * 4 + r;
                    if (hiLane && j < J) y[yb + j] = acc[sc][tt][r] + lo * (1.f / 1024.f);
                }
            }
        }
    }
}

// K3: BN stats, two stage (partial over 128-tb chunks, then final)
__global__ __launch_bounds__(256) void k3_partial(
        const float* __restrict__ y, float* __restrict__ psum) {
    int ih = blockIdx.x, ck = blockIdx.y;
    int i = ih >> 3, h = ih & 7;
    int J = 50 - i;
    size_t yb = yoff(i);
    int tid = threadIdx.x;
    int grp = tid >> 5, sub = tid & 31;
    float sm = 0.f, ss = 0.f;
    for (int tb = ck * 128 + grp; tb < (ck + 1) * 128; tb += 8) {
        const float* row = y + yb + ((size_t)tb * NH + h) * J;
        for (int j = sub; j < J; j += 32) { float v = row[j]; sm += v; ss += v * v; }
    }
    __shared__ float r1[4], r2[4];
    float a = waveSum(sm), b = waveSum(ss);
    int wid = tid >> 6, lane = tid & 63;
    if (lane == 0) { r1[wid] = a; r2[wid] = b; }
    __syncthreads();
    if (tid == 0) {
        psum[((size_t)ih * 8 + ck) * 2]     = r1[0] + r1[1] + r1[2] + r1[3];
        psum[((size_t)ih * 8 + ck) * 2 + 1] = r2[0] + r2[1] + r2[2] + r2[3];
    }
}

__global__ __launch_bounds__(256) void k3_final(
        const float* __restrict__ psum, const float* __restrict__ bng,
        float* __restrict__ statm, float* __restrict__ stats_) {
    int ih = blockIdx.x * 256 + threadIdx.x;
    if (ih >= 400) return;
    float S = 0.f, Q = 0.f;
    for (int ck = 0; ck < 8; ++ck) {
        S += psum[((size_t)ih * 8 + ck) * 2];
        Q += psum[((size_t)ih * 8 + ck) * 2 + 1];
    }
    int i = ih >> 3;
    float cnt = 1024.f * (float)(50 - i);
    float m = S / cnt;
    float var = Q / cnt - m * m; if (var < 0.f) var = 0.f;
    statm[ih] = m;
    stats_[ih] = bng[ih] / sqrtf(var + EPSF);
}

// K4: BN + LIF over t + max-pool over j -> poolsum [B,400]
__global__ __launch_bounds__(512) void k4_bn_lif_pool(
        const float* __restrict__ y, const float* __restrict__ statm,
        const float* __restrict__ stats_, const float* __restrict__ bnb,
        float* __restrict__ ps) {
    int b = blockIdx.x, i = blockIdx.y, J = L_ - i;
    int h = threadIdx.x >> 6, lane = threadIdx.x & 63;
    int ih = i * NH + h;
    float m = statm[ih], sc = stats_[ih], bb = bnb[ih];
    size_t yb = yoff(i);
    bool valid = lane < J;
    float v = 0.f; int cnt = 0;
    #pragma unroll
    for (int t = 0; t < T_; ++t) {
        int tb = t * B_ + b;
        float yn;
        if (valid) {
            float raw = y[yb + ((size_t)tb * NH + h) * J + lane];
            yn = (raw - m) * sc + bb;
        } else yn = -1e30f;
        v += (yn - v) * 0.5f;
        bool sp = (v >= 1.f);
        if (sp) v = 0.f;
        if (__any(sp)) cnt++;
    }
    if (lane == 0) ps[(size_t)b * 400 + ih] = (float)cnt;
}

// K5: fused heads
__global__ __launch_bounds__(128) void k5_final(
        const float* __restrict__ smean, const float* __restrict__ ps,
        const float* __restrict__ convv, const float* __restrict__ fchw,
        const float* __restrict__ fchb, const float* __restrict__ fcvw,
        const float* __restrict__ fcvb, float* __restrict__ out) {
    __shared__ float sm_l[L_ * D_];
    __shared__ float vm[NV * D_];
    __shared__ float ps_l[400];
    int b = blockIdx.x, tid = threadIdx.x;
    for (int idx = tid; idx < L_ * D_; idx += 128) sm_l[idx] = smean[(size_t)b * (L_ * D_) + idx];
    for (int idx = tid; idx < 400; idx += 128) ps_l[idx] = ps[(size_t)b * 400 + idx];
    __syncthreads();
    int d = tid;
    #pragma unroll
    for (int c = 0; c < NV; ++c) {
        float a = 0.f;
        for (int l = 0; l < L_; ++l) a += convv[c * L_ + l] * sm_l[l * D_ + d];
        vm[c * D_ + d] = a;
    }
    __syncthreads();
    float acc = fchb[d] + fcvb[d];
    float ah = 0.f;
    for (int ih = 0; ih < 400; ++ih) ah += ps_l[ih] * fchw[d * 400 + ih];
    acc += ah * 0.25f;
    float av = 0.f;
    for (int cd = 0; cd < NV * D_; ++cd) av += vm[cd] * fcvw[d * (NV * D_) + cd];
    acc += av;
    out[(size_t)b * D_ + d] = acc;
}

extern "C" void kernel_launch(void* const* d_in, const int* in_sizes, int n_in,
                              void* d_out, int out_size, void* d_ws, size_t ws_size,
                              hipStream_t stream) {
    const int*   item  = (const int*)d_in[0];
    const float* tab   = (const float*)d_in[1];
    const float* lng   = (const float*)d_in[2];
    const float* lnb   = (const float*)d_in[3];
    const float* convv = (const float*)d_in[4];
    const float* convh = (const float*)d_in[5];
    const float* bng   = (const float*)d_in[6];
    const float* bnb   = (const float*)d_in[7];
    const float* fchw  = (const float*)d_in[8];
    const float* fchb  = (const float*)d_in[9];
    const float* fcvw  = (const float*)d_in[10];
    const float* fcvb  = (const float*)d_in[11];
    float* out = (float*)d_out;

    char* ws = (char*)d_ws;
    // layout (bytes):
    // s16    @ 0          13,107,200   fp16 spikes, pre-swizzled granules
    // smean  @ 13107200    6,553,600
    // y      @ 19660800   41,779,200
    // whl    @ 61440000   10,649,600   fp16 hi/lo weights [52][50][16][128], zero-padded
    // statm  @ 72089600        1,600
    // stats_ @ 72091200        1,600
    // ps     @ 72092800      409,600
    // psum   @ 72502400       25,600   -> total 72,528,000
    _Float16* s16  = (_Float16*)(ws);
    float* smean   = (float*)(ws + 13107200LL);
    float* y       = (float*)(ws + 19660800LL);
    _Float16* whl  = (_Float16*)(ws + 61440000LL);
    float* statm   = (float*)(ws + 72089600LL);
    float* stats_  = (float*)(ws + 72091200LL);
    float* ps      = (float*)(ws + 72092800LL);
    float* psum    = (float*)(ws + 72502400LL);

    hipFuncSetAttribute(reinterpret_cast<const void*>(&k2z),
        hipFuncAttributeMaxDynamicSharedMemorySize, 102400);

    k0_wsplit<<<dim3(50, 52), 256, 0, stream>>>(convh, whl);
    k1_embed_ln_lif<<<B_ * L_, 128, 0, stream>>>(item, tab, lng, lnb, s16, smean);
    k2z<<<dim3(128, 28), 512, 102400, stream>>>(s16, whl, y);
    k3_partial<<<dim3(400, 8), 256, 0, stream>>>(y, psum);
    k3_final<<<dim3(2, 1), 256, 0, stream>>>(psum, bng, statm, stats_);
    k4_bn_lif_pool<<<dim3(B_, L_), 512, 0, stream>>>(y, statm, stats_, bnb, ps);
    k5_final<<<B_, 128, 0, stream>>>(smean, ps, convv, fchw, fchb, fcvw, fcvb, out);
}